// Round 2
// baseline (20125.041 us; speedup 1.0000x reference)
//
#include <hip/hip_runtime.h>
#include <hip/hip_bf16.h>
#include <hip/hip_cooperative_groups.h>

namespace cg = cooperative_groups;

// Problem constants
constexpr int NB   = 32;    // batch
constexpr int NT   = 512;   // tokens
constexpr int ND   = 768;   // bert dim
constexpr int NW   = 255;   // words
constexpr int NH   = 768;   // lstm hidden
constexpr int NCLS = 9;     // NER classes
constexpr int NMTOT = NB * NW;          // 8160 rows
constexpr int NG4  = 4 * NH;            // 3072 gate dim

__device__ __forceinline__ float sigmoidf_(float x) {
    return 1.0f / (1.0f + expf(-x));
}

// ---------------------------------------------------------------------------
// Kernel 1: first-subword index per (b, w) -> rowbase[m] = element offset into
// bert_out of the pooled row for m = b*NW + w.  (argmax(eq, axis=1) semantics:
// first t with word_ids[b,t]==w, else 0.)
// ---------------------------------------------------------------------------
__global__ void pool_idx_kernel(const int* __restrict__ word_ids,
                                int* __restrict__ rowbase) {
    int bb = blockIdx.x;
    int w = threadIdx.x;
    if (w >= NW) return;
    const int* row = word_ids + bb * NT;
    int ft = 0;
    for (int t = 0; t < NT; ++t) {
        if (row[t] == w) { ft = t; break; }
    }
    rowbase[bb * NW + w] = (bb * NT + ft) * ND;
}

// ---------------------------------------------------------------------------
// Kernel 2: xg[dir] = pooled @ W_ih[dir]^T + b[dir]   (f32)
// M=8160 (gathered rows), N=3072, K=768. 128x128 tile, BK=8, 8x8 per thread.
// grid = (24, 64, 2), block = 256.
// ---------------------------------------------------------------------------
__global__ __launch_bounds__(256) void gemm_xg_kernel(
    const float* __restrict__ bert, const int* __restrict__ rowbase,
    const float* __restrict__ Wf, const float* __restrict__ biasf,
    const float* __restrict__ Wb, const float* __restrict__ biasb,
    float* __restrict__ xgf, float* __restrict__ xgb) {
    const int dir = blockIdx.z;
    const float* Wt = dir ? Wb : Wf;
    const float* bias = dir ? biasb : biasf;
    float* xg = dir ? xgb : xgf;
    const int m0 = blockIdx.y * 128;
    const int n0 = blockIdx.x * 128;

    __shared__ float As[8][128];
    __shared__ float Bs[8][128];

    const int t = threadIdx.x;
    const int lrow = t >> 1;        // 0..127
    const int lk = (t & 1) * 4;     // 0 or 4

    int am = m0 + lrow;
    const float* aptr = bert + (am < NMTOT ? rowbase[am] : rowbase[NMTOT - 1]) + lk;
    const float* bptr = Wt + (size_t)(n0 + lrow) * ND + lk;

    const int tm = (t & 15) * 8;
    const int tn = (t >> 4) * 8;

    float acc[8][8] = {};

    for (int k0 = 0; k0 < ND; k0 += 8) {
        float4 av = *(const float4*)(aptr + k0);
        float4 bv = *(const float4*)(bptr + k0);
        __syncthreads();
        As[lk + 0][lrow] = av.x; As[lk + 1][lrow] = av.y;
        As[lk + 2][lrow] = av.z; As[lk + 3][lrow] = av.w;
        Bs[lk + 0][lrow] = bv.x; Bs[lk + 1][lrow] = bv.y;
        Bs[lk + 2][lrow] = bv.z; Bs[lk + 3][lrow] = bv.w;
        __syncthreads();
#pragma unroll
        for (int kk = 0; kk < 8; ++kk) {
            float ar[8], br[8];
#pragma unroll
            for (int i = 0; i < 8; ++i) ar[i] = As[kk][tm + i];
#pragma unroll
            for (int j = 0; j < 8; ++j) br[j] = Bs[kk][tn + j];
#pragma unroll
            for (int i = 0; i < 8; ++i)
#pragma unroll
                for (int j = 0; j < 8; ++j)
                    acc[i][j] = fmaf(ar[i], br[j], acc[i][j]);
        }
    }

#pragma unroll
    for (int i = 0; i < 8; ++i) {
        int m = m0 + tm + i;
        if (m >= NMTOT) continue;
        float* orow = xg + (size_t)m * NG4 + n0 + tn;
#pragma unroll
        for (int j = 0; j < 8; ++j) orow[j] = acc[i][j] + bias[n0 + tn + j];
    }
}

// ---------------------------------------------------------------------------
// Kernel 3: persistent cooperative bidirectional LSTM recurrence.
// 384 blocks x 128 threads; block = (dir = blk/192, col-slice cb = blk%192,
// cols cb*4 .. cb*4+3). W_hh slice staged in LDS as Wl[ci][k][gate]
// (4*768*4*4B = 48 KiB <= 64 KiB limit).
// Thread t: lb = t&31 (batch), ci = t>>5 (0..3 local col); owns (col, lb);
// cell state c lives in a register across all 255 steps.
// h double-buffered in ws, layout [k][b] (k-major) for coalesced broadcast.
// One grid.sync per step.
// ---------------------------------------------------------------------------
__global__ __launch_bounds__(128) void lstm_kernel(
    const float* __restrict__ xgf, const float* __restrict__ xgb,
    const float* __restrict__ Whf, const float* __restrict__ Whb,
    float* __restrict__ hf_out, float* __restrict__ hb_out,
    float* __restrict__ hbuf /* [2 dir][2 buf][NH*NB] */) {
    extern __shared__ float Wl[];  // [4][NH][4] = 12288 floats = 49152 B

    cg::grid_group grid = cg::this_grid();
    const int blk = blockIdx.x;       // 0..383
    const int dir = blk / 192;
    const int cb = blk % 192;
    const int t = threadIdx.x;        // 0..127
    const int lb = t & 31;            // batch lane
    const int ci = t >> 5;            // 0..3 local col
    const int col = cb * 4 + ci;

    const float* Wh = dir ? Whb : Whf;
    const float* xg = dir ? xgb : xgf;
    float* hout = dir ? hb_out : hf_out;

    // Stage W_hh slice: Wl[ci][k][g] = Wh[g*NH + col][k]
    {
        int r = t >> 3;               // 0..15 = (ci2, g)
        int ci2 = r >> 2, g = r & 3;
        int col2 = cb * 4 + ci2;
        const float* src = Wh + (size_t)(g * NH + col2) * NH;
        int tsub = t & 7;
        for (int kq = tsub * 4; kq < NH; kq += 32) {
            float4 v = *(const float4*)(src + kq);
            float* dst = Wl + (size_t)(ci2 * NH + kq) * 4 + g;
            dst[0] = v.x; dst[4] = v.y; dst[8] = v.z; dst[12] = v.w;
        }
    }
    // Zero h double-buffers (ws is poisoned before every call)
    {
        int idx = blk * 128 + t;
        for (int i = idx; i < 4 * NH * NB; i += 384 * 128) hbuf[i] = 0.0f;
    }
    __syncthreads();
    grid.sync();

    float c = 0.0f;
    float* hbase = hbuf + (size_t)dir * 2 * NH * NB;
    const float* wp = Wl + (size_t)ci * NH * 4;

    for (int s = 0; s < NW; ++s) {
        const int p = dir ? (NW - 1 - s) : s;
        const size_t mrow = (size_t)(lb * NW + p) * NG4 + col;
        // issue xg loads early; consumed only after the k-loop
        float xi = xg[mrow];
        float xf = xg[mrow + NH];
        float xgg = xg[mrow + 2 * NH];
        float xo = xg[mrow + 3 * NH];

        const float* hr = hbase + (s & 1) * (NH * NB);
        float ai = 0.f, af = 0.f, ag = 0.f, ao = 0.f;
#pragma unroll 8
        for (int k = 0; k < NH; ++k) {
            float hv = hr[k * 32 + lb];
            float4 w4 = *(const float4*)(wp + k * 4);
            ai = fmaf(hv, w4.x, ai);
            af = fmaf(hv, w4.y, af);
            ag = fmaf(hv, w4.z, ag);
            ao = fmaf(hv, w4.w, ao);
        }
        float iG = sigmoidf_(ai + xi);
        float fG = sigmoidf_(af + xf);
        float gG = tanhf(ag + xgg);
        float oG = sigmoidf_(ao + xo);
        c = fG * c + iG * gG;
        float h = oG * tanhf(c);

        float* hw = hbase + ((s + 1) & 1) * (NH * NB);
        hw[col * 32 + lb] = h;
        hout[(size_t)(lb * NW + p) * NH + col] = h;
        grid.sync();
    }
}

// ---------------------------------------------------------------------------
// Kernel 4: head — logits = [h_f, h_b] @ W_lin^T + b_lin; softmax; argmax.
// One wave per row m. Output buffer is FLOAT32: prob [8160*9] then path [8160].
// ---------------------------------------------------------------------------
__global__ __launch_bounds__(64) void head_kernel(
    const float* __restrict__ hf, const float* __restrict__ hb,
    const float* __restrict__ Wl, const float* __restrict__ bl,
    float* __restrict__ out) {
    const int m = blockIdx.x;      // 0..8159
    const int lane = threadIdx.x;  // 0..63
    float acc[NCLS];
#pragma unroll
    for (int cI = 0; cI < NCLS; ++cI) acc[cI] = 0.0f;

    const float* hfr = hf + (size_t)m * NH;
    const float* hbr = hb + (size_t)m * NH;
    for (int j = lane; j < NH; j += 64) {
        float v1 = hfr[j];
        float v2 = hbr[j];
#pragma unroll
        for (int cI = 0; cI < NCLS; ++cI) {
            acc[cI] = fmaf(v1, Wl[cI * 2 * NH + j], acc[cI]);
            acc[cI] = fmaf(v2, Wl[cI * 2 * NH + NH + j], acc[cI]);
        }
    }
#pragma unroll
    for (int cI = 0; cI < NCLS; ++cI)
        for (int off = 32; off > 0; off >>= 1)
            acc[cI] += __shfl_down(acc[cI], off);

    if (lane == 0) {
        float logit[NCLS];
        float mx = -1e30f;
#pragma unroll
        for (int cI = 0; cI < NCLS; ++cI) {
            logit[cI] = acc[cI] + bl[cI];
            mx = fmaxf(mx, logit[cI]);
        }
        float e[NCLS];
        float sum = 0.0f;
#pragma unroll
        for (int cI = 0; cI < NCLS; ++cI) { e[cI] = expf(logit[cI] - mx); sum += e[cI]; }
        float inv = 1.0f / sum;
        int best = 0;
        float bestv = -1.0f;
#pragma unroll
        for (int cI = 0; cI < NCLS; ++cI) {
            float p = e[cI] * inv;
            out[(size_t)m * NCLS + cI] = p;
            if (p > bestv) { bestv = p; best = cI; }  // first-occurrence argmax
        }
        out[(size_t)NMTOT * NCLS + m] = (float)best;
    }
}

// ---------------------------------------------------------------------------
extern "C" void kernel_launch(void* const* d_in, const int* in_sizes, int n_in,
                              void* d_out, int out_size, void* d_ws, size_t ws_size,
                              hipStream_t stream) {
    const float* bert     = (const float*)d_in[0];
    const int*   word_ids = (const int*)d_in[1];
    const float* W_ih_f   = (const float*)d_in[2];
    const float* W_hh_f   = (const float*)d_in[3];
    const float* b_f      = (const float*)d_in[4];
    const float* W_ih_b   = (const float*)d_in[5];
    const float* W_hh_b   = (const float*)d_in[6];
    const float* b_b      = (const float*)d_in[7];
    const float* W_lin    = (const float*)d_in[8];
    const float* b_lin    = (const float*)d_in[9];
    float* out = (float*)d_out;   // f32: prob [8160*9] then path [8160]

    char* ws = (char*)d_ws;
    size_t off = 0;
    auto alloc = [&](size_t bytes) -> void* {
        void* p = ws + off;
        off += (bytes + 255) & ~(size_t)255;
        return p;
    };
    int*   rowbase = (int*)alloc((size_t)NMTOT * sizeof(int));
    float* xgf = (float*)alloc((size_t)NMTOT * NG4 * sizeof(float));   // 100 MB
    float* xgb = (float*)alloc((size_t)NMTOT * NG4 * sizeof(float));   // 100 MB
    float* hf  = (float*)alloc((size_t)NMTOT * NH * sizeof(float));    // 25 MB
    float* hb  = (float*)alloc((size_t)NMTOT * NH * sizeof(float));    // 25 MB
    float* hbuf = (float*)alloc((size_t)4 * NH * NB * sizeof(float));  // 384 KB

    pool_idx_kernel<<<NB, 256, 0, stream>>>(word_ids, rowbase);

    dim3 ggrid(NG4 / 128, (NMTOT + 127) / 128, 2);
    gemm_xg_kernel<<<ggrid, 256, 0, stream>>>(bert, rowbase, W_ih_f, b_f,
                                              W_ih_b, b_b, xgf, xgb);

    void* args[] = { (void*)&xgf, (void*)&xgb, (void*)&W_hh_f, (void*)&W_hh_b,
                     (void*)&hf, (void*)&hb, (void*)&hbuf };
    hipLaunchCooperativeKernel((const void*)lstm_kernel, dim3(384), dim3(128),
                               args, 4 * NH * 4 * sizeof(float), stream);

    head_kernel<<<NMTOT, 64, 0, stream>>>(hf, hb, W_lin, b_lin, out);
}